// Round 8
// baseline (116.276 us; speedup 1.0000x reference)
//
#include <hip/hip_runtime.h>

#define T_SEQ 4096
#define BATCH 4
#define DD 128
#define BT (BATCH * T_SEQ)
#define MAXPARTS 4        // groups split into sg/8+1 <= 4 balanced parts

typedef __bf16 bf16x8 __attribute__((ext_vector_type(8)));
typedef float f32x4 __attribute__((ext_vector_type(4)));

__device__ inline bf16x8 ld8(const unsigned short* p) {
  return *reinterpret_cast<const bf16x8*>(p);
}
__device__ inline unsigned short bfc(float f) {
  __bf16 v = (__bf16)f;
  return __builtin_bit_cast(unsigned short, v);
}
__device__ inline float fexp2(float x) {
  float r;
  asm("v_exp_f32 %0, %1" : "=v"(r) : "v"(x));
  return r;
}
// V-buffer swizzle: XOR the 16B slot (bits 3-4 of the short index) with
// (row>>1)&3 so 16 lanes reading different rows at one column hit distinct
// bank quads (residual 2-way aliasing is free). Row = 32 shorts = 64 B.
__device__ inline int vsw(int sIdx) {
  return sIdx ^ ((((sIdx >> 6) & 3) << 3));
}

#define MFMA(a, b, c) __builtin_amdgcn_mfma_f32_16x16x32_bf16((a), (b), (c), 0, 0, 0)

// ---- W (128x128 f32, [d][u]) -> frag-major bf16:
// F[((n0*4+c)*64 + lane)*8 + j] = W[(c*32+g*8+j)*128 + n0*16+t], lane=(g<<4)|t.
__global__ void wt_kernel(const float* __restrict__ Wq, const float* __restrict__ Wk,
                          const float* __restrict__ Wv,
                          unsigned short* __restrict__ fq, unsigned short* __restrict__ fk,
                          unsigned short* __restrict__ fv) {
  const float* W = (blockIdx.y == 0) ? Wq : (blockIdx.y == 1) ? Wk : Wv;
  unsigned short* F = (blockIdx.y == 0) ? fq : (blockIdx.y == 1) ? fk : fv;
  int e = blockIdx.x * 256 + threadIdx.x;          // 0..16383
  int j = e & 7, lane = (e >> 3) & 63, nc = e >> 9;
  int c = nc & 3, n0 = nc >> 2;
  int t = lane & 15, g = lane >> 4;
  F[e] = bfc(W[(c * 32 + g * 8 + j) * 128 + n0 * 16 + t]);
}

// ---- projections, W-STATIONARY (unchanged, proven). qf folds (1/64)*log2(e).
__global__ __launch_bounds__(256) void proj_kernel(
    const float* __restrict__ X,
    const unsigned short* __restrict__ fq,
    const unsigned short* __restrict__ fk,
    const unsigned short* __restrict__ fv,
    unsigned short* __restrict__ qf,
    unsigned short* __restrict__ kf,
    unsigned short* __restrict__ vt) {
  const int tid = threadIdx.x;
  const int w = tid >> 6, lane = tid & 63;
  const int t = lane & 15, g = lane >> 4;
  const int r0 = blockIdx.x * 32;   // 512 blocks x 32 rows

  __shared__ unsigned short xs[2][16 * 136];

  bf16x8 wq[2][4], wk[2][4], wv[2][4];
#pragma unroll
  for (int s = 0; s < 2; ++s)
#pragma unroll
    for (int c = 0; c < 4; ++c) {
      int fo = (((w + s * 4) * 4 + c) * 64 + lane) * 8;
      wq[s][c] = ld8(fq + fo);
      wk[s][c] = ld8(fk + fo);
      wv[s][c] = ld8(fv + fo);
    }

#pragma unroll
  for (int sub = 0; sub < 2; ++sub) {
    int r = tid >> 4, cb = tid & 15;
    const float* xp = X + (size_t)(r0 + sub * 16 + r) * DD + cb * 8;
    float4 lo = *reinterpret_cast<const float4*>(xp);
    float4 hi = *reinterpret_cast<const float4*>(xp + 4);
    bf16x8 tmp;
    tmp[0] = (__bf16)lo.x; tmp[1] = (__bf16)lo.y; tmp[2] = (__bf16)lo.z; tmp[3] = (__bf16)lo.w;
    tmp[4] = (__bf16)hi.x; tmp[5] = (__bf16)hi.y; tmp[6] = (__bf16)hi.z; tmp[7] = (__bf16)hi.w;
    *reinterpret_cast<bf16x8*>(&xs[sub][r * 136 + cb * 8]) = tmp;
  }
  __syncthreads();

#pragma unroll
  for (int sub = 0; sub < 2; ++sub) {
    const int r0s = r0 + sub * 16;
    bf16x8 x[4];
#pragma unroll
    for (int c = 0; c < 4; ++c)
      x[c] = ld8(&xs[sub][t * 136 + c * 32 + g * 8]);

#pragma unroll
    for (int s = 0; s < 2; ++s) {
      const int n0 = w + s * 4;
      f32x4 aq = {0.f, 0.f, 0.f, 0.f}, ak = {0.f, 0.f, 0.f, 0.f};
#pragma unroll
      for (int c = 0; c < 4; ++c) {
        aq = MFMA(x[c], wq[s][c], aq);
        ak = MFMA(x[c], wk[s][c], ak);
      }
      const int cP = n0 >> 1;
      const int Gp = ((n0 & 1) << 1) | (t >> 3);
      const int ep = t & 7;
#pragma unroll
      for (int r = 0; r < 4; ++r) {
        int row = r0s + g * 4 + r;
        size_t qoff = ((size_t)((row >> 4) * 4 + cP) * 64 + ((Gp << 4) | (row & 15))) * 8 + ep;
        qf[qoff] = bfc(aq[r] * 0.0225421101f);   // (1/64) * log2(e)
        int tp = (row & 3) | (((row >> 3) & 3) << 2);
        size_t koff =
            ((size_t)(((row >> 5) * 2 + ((row >> 2) & 1)) * 4 + cP) * 64 + ((Gp << 4) | tp)) * 8 +
            ep;
        kf[koff] = bfc(ak[r]);
      }
    }

    const int key = r0s + t;
    const size_t vbase = (size_t)(key >> 5) * 4096 + (key & 31);
#pragma unroll
    for (int s = 0; s < 2; ++s) {
      const int u0 = w + s * 4;
      f32x4 av = {0.f, 0.f, 0.f, 0.f};
#pragma unroll
      for (int c = 0; c < 4; ++c)
        av = MFMA(wv[s][c], x[c], av);
#pragma unroll
      for (int r = 0; r < 4; ++r)
        vt[vbase + (size_t)(u0 * 16 + g * 4 + r) * 32] = bfc(av[r]);
    }
  }
}

// ---- flash attention, LDS-shared K/V with whole-group ownership: a block's
// 4 waves process the SAME 32-key chunk for the 4 tiles of one 128-row
// q-group (wave w owns tile 4*sg+w). Per chunk the block stages 16 KB once
// (reg-staged split, double-buffered, one barrier/chunk) -- r7's proven loop.
// NEW decomposition (kills r7's 53 MB partial tax): each block owns ONE
// contiguous chunk-range of ONE group; group sg splits into sg/8+1 <= 4
// balanced parts => max 32 serial chunks/block, partials only for sg>=8
// (18 MB total). Per batch: octet o contributes 8*(o+1) blocks => 80; grid
// 320, all co-resident at 2 blocks/CU. Work-descending dispatch (a=79-k)
// makes the 64 double-resident CUs pair a big part with a tiny octet-0 group.
__global__ __launch_bounds__(256, 2) void attn_kernel(
    const unsigned short* __restrict__ qf,
    const unsigned short* __restrict__ kf,
    const unsigned short* __restrict__ vt,
    float* __restrict__ pO,
    float* __restrict__ pL,
    float* __restrict__ out) {
  const int tid = threadIdx.x;
  const int w = tid >> 6, lane = tid & 63;
  const int t = lane & 15, G = lane >> 4;
  const int bi = blockIdx.x;
  const int xcd = bi & 7;                      // assumed round-robin XCD mapping
  const int b = xcd >> 1;                      // batch pinned to an XCD pair (L2)
  const int k = ((bi >> 3) << 1) | (xcd & 1);  // 0..79 batch-local block index

  // decode: a=79-k ascending-enum index -> (octet o, group sg, part p)
  const int a = 79 - k;
  int o = 0;
  while (4 * (o + 1) * (o + 2) <= a) ++o;      // o in 0..3
  const int idx = a - 4 * o * (o + 1);
  const int sg = 8 * o + idx / (o + 1);
  const int p = idx % (o + 1);
  const int parts = o + 1;
  const int N = 4 * sg + 4;                    // chunks in this group
  const int qn = N / parts, rem = N % parts;   // balanced split
  const int jlo = p * qn + min(p, rem);
  const int jhi = jlo + qn + (p < rem ? 1 : 0);

  const int sig32 = 4 * sg + w;                // this wave's 32-row tile
  const int q0 = sig32 * 32;

  const unsigned short* kfb = kf + (size_t)b * (T_SEQ * DD);
  const unsigned short* vtb = vt + (size_t)b * (T_SEQ * DD);

  __shared__ unsigned short bufK[2][4096], bufV[2][4096];

  // Q fragments for tiles 2*sig32, 2*sig32+1
  bf16x8 qa[2][4];
#pragma unroll
  for (int pp = 0; pp < 2; ++pp)
#pragma unroll
    for (int c = 0; c < 4; ++c)
      qa[pp][c] = ld8(qf + ((size_t)((b * 256 + 2 * sig32 + pp) * 4 + c) * 64 + lane) * 8);

  f32x4 O[2][8];
#pragma unroll
  for (int pp = 0; pp < 2; ++pp)
#pragma unroll
    for (int u0 = 0; u0 < 8; ++u0) O[pp][u0] = (f32x4){0.f, 0.f, 0.f, 0.f};
  float ls0 = 0.f, ls1 = 0.f;

  // ---- prologue: stage chunk jlo into buf 0 (16KB: each thread 4 x 16B)
  bf16x8 st0, st1, st2, st3;
  {
    const unsigned short* kch = kfb + (size_t)jlo * 4096;
    const unsigned short* vch = vtb + (size_t)jlo * 4096;
    st0 = ld8(kch + tid * 8);
    st1 = ld8(kch + 2048 + tid * 8);
    st2 = ld8(vch + tid * 8);
    st3 = ld8(vch + 2048 + tid * 8);
    *reinterpret_cast<bf16x8*>(&bufK[0][tid * 8]) = st0;
    *reinterpret_cast<bf16x8*>(&bufK[0][2048 + tid * 8]) = st1;
    *reinterpret_cast<bf16x8*>(&bufV[0][vsw(tid * 8)]) = st2;
    *reinterpret_cast<bf16x8*>(&bufV[0][vsw(2048 + tid * 8)]) = st3;
  }
  __syncthreads();

  int cur = 0;
  for (int j = jlo; j < jhi; ++j) {
    const bool more = (j + 1 < jhi);
    // issue next-chunk stage loads (consumed by ds_write after compute)
    if (more) {
      const unsigned short* kch = kfb + (size_t)(j + 1) * 4096;
      const unsigned short* vch = vtb + (size_t)(j + 1) * 4096;
      st0 = ld8(kch + tid * 8);
      st1 = ld8(kch + 2048 + tid * 8);
      st2 = ld8(vch + tid * 8);
      st3 = ld8(vch + 2048 + tid * 8);
    }

    // ---- compute chunk j from LDS (skip if fully masked for this wave)
    if (j <= sig32) {
      f32x4 s00 = {0.f, 0.f, 0.f, 0.f}, s01 = {0.f, 0.f, 0.f, 0.f};
      f32x4 s10 = {0.f, 0.f, 0.f, 0.f}, s11 = {0.f, 0.f, 0.f, 0.f};
      {
        bf16x8 kc[4];
#pragma unroll
        for (int c = 0; c < 4; ++c) kc[c] = ld8(&bufK[cur][c * 512 + lane * 8]);
#pragma unroll
        for (int c = 0; c < 4; ++c) {
          s00 = MFMA(kc[c], qa[0][c], s00);
          s10 = MFMA(kc[c], qa[1][c], s10);
        }
#pragma unroll
        for (int c = 0; c < 4; ++c) kc[c] = ld8(&bufK[cur][(4 + c) * 512 + lane * 8]);
#pragma unroll
        for (int c = 0; c < 4; ++c) {
          s01 = MFMA(kc[c], qa[0][c], s01);
          s11 = MFMA(kc[c], qa[1][c], s11);
        }
      }

      bf16x8 pb0, pb1;
      if (j < sig32) {
        // fully-unmasked chunk: no causal compares
#pragma unroll
        for (int r = 0; r < 4; ++r) {
          float e00 = fexp2(s00[r]), e01 = fexp2(s01[r]);
          float e10 = fexp2(s10[r]), e11 = fexp2(s11[r]);
          ls0 += e00 + e01;
          ls1 += e10 + e11;
          pb0[r] = (__bf16)e00; pb0[r + 4] = (__bf16)e01;
          pb1[r] = (__bf16)e10; pb1[r + 4] = (__bf16)e11;
        }
      } else {
        // diagonal chunk (j == sig32)
#pragma unroll
        for (int r = 0; r < 4; ++r) {
          int k0 = j * 32 + G * 8 + r;
          float e00 = (k0 <= q0 + t) ? fexp2(s00[r]) : 0.f;
          float e01 = (k0 + 4 <= q0 + t) ? fexp2(s01[r]) : 0.f;
          float e10 = (k0 <= q0 + 16 + t) ? fexp2(s10[r]) : 0.f;
          float e11 = (k0 + 4 <= q0 + 16 + t) ? fexp2(s11[r]) : 0.f;
          ls0 += e00 + e01;
          ls1 += e10 + e11;
          pb0[r] = (__bf16)e00; pb0[r + 4] = (__bf16)e01;
          pb1[r] = (__bf16)e10; pb1[r + 4] = (__bf16)e11;
        }
      }

#pragma unroll
      for (int u0 = 0; u0 < 8; ++u0) {
        bf16x8 vcu = ld8(&bufV[cur][vsw((u0 * 16 + t) * 32 + G * 8)]);
        O[0][u0] = MFMA(pb0, vcu, O[0][u0]);
        O[1][u0] = MFMA(pb1, vcu, O[1][u0]);
      }
    }

    // ---- write staged chunk j+1 into the other buffer, then barrier
    if (more) {
      const int nxt = cur ^ 1;
      *reinterpret_cast<bf16x8*>(&bufK[nxt][tid * 8]) = st0;
      *reinterpret_cast<bf16x8*>(&bufK[nxt][2048 + tid * 8]) = st1;
      *reinterpret_cast<bf16x8*>(&bufV[nxt][vsw(tid * 8)]) = st2;
      *reinterpret_cast<bf16x8*>(&bufV[nxt][vsw(2048 + tid * 8)]) = st3;
      __syncthreads();
      cur ^= 1;
    }
  }

  // ---- epilogue: one flush per block
  float r0s = ls0; r0s += __shfl_xor(r0s, 16); r0s += __shfl_xor(r0s, 32);
  float r1s = ls1; r1s += __shfl_xor(r1s, 16); r1s += __shfl_xor(r1s, 32);
  if (parts == 1) {
    // whole group in this block: each wave normalizes + stores its tile
    float linv0[4], linv1[4];
#pragma unroll
    for (int r = 0; r < 4; ++r) {
      linv0[r] = 1.0f / __shfl(r0s, G * 4 + r);
      linv1[r] = 1.0f / __shfl(r1s, G * 4 + r);
    }
    float* op0 = out + ((size_t)(b * T_SEQ + q0 + G * 4)) * DD + t;
    float* op1 = op0 + (size_t)16 * DD;
#pragma unroll
    for (int u0 = 0; u0 < 8; ++u0) {
#pragma unroll
      for (int r = 0; r < 4; ++r) {
        op0[(size_t)r * DD + u0 * 16] = O[0][u0][r] * linv0[r];
        op1[(size_t)r * DD + u0 * 16] = O[1][u0][r] * linv1[r];
      }
    }
  } else {
    // split group: raw per-wave partial to workspace slot (b, sig32, p)
    const int slot = (b * 128 + sig32) * MAXPARTS + p;
    if (lane < 16) {
      pL[slot * 32 + lane] = r0s;
      pL[slot * 32 + 16 + lane] = r1s;
    }
    float* pb = pO + (size_t)slot * 4096 + (size_t)(G * 4) * DD + t;
#pragma unroll
    for (int u0 = 0; u0 < 8; ++u0) {
#pragma unroll
      for (int r = 0; r < 4; ++r) {
        pb[(size_t)r * DD + u0 * 16] = O[0][u0][r];
        pb[(size_t)(16 + r) * DD + u0 * 16] = O[1][u0][r];
      }
    }
  }
}

// ---- combine split groups: sum <=4 per-part partials, normalize, store.
__global__ __launch_bounds__(256) void comb_kernel(const float* __restrict__ pO,
                                                   const float* __restrict__ pL,
                                                   float* __restrict__ out) {
  const int bi = blockIdx.x;          // 512: b = bi>>7, sig32 = bi&127
  const int b = bi >> 7, sig32 = bi & 127;
  const int sg = sig32 >> 2;
  const int parts = sg / 8 + 1;
  if (parts == 1) return;             // handled directly by attn_kernel
  const int tid = threadIdx.x;
  const int q = tid >> 3, uc = (tid & 7) * 16;
  const int slot0 = (b * 128 + sig32) * MAXPARTS;

  float ls = 0.f;
  for (int p = 0; p < parts; ++p) ls += pL[(slot0 + p) * 32 + q];
  const float linv = 1.0f / ls;

  float4 acc[4] = {{0,0,0,0},{0,0,0,0},{0,0,0,0},{0,0,0,0}};
  for (int p = 0; p < parts; ++p) {
    const float* src = pO + (size_t)(slot0 + p) * 4096 + (size_t)q * DD + uc;
#pragma unroll
    for (int e = 0; e < 4; ++e) {
      float4 v = *reinterpret_cast<const float4*>(src + e * 4);
      acc[e].x += v.x; acc[e].y += v.y; acc[e].z += v.z; acc[e].w += v.w;
    }
  }
  float* dst = out + ((size_t)(b * T_SEQ + sig32 * 32 + q)) * DD + uc;
#pragma unroll
  for (int e = 0; e < 4; ++e) {
    acc[e].x *= linv; acc[e].y *= linv; acc[e].z *= linv; acc[e].w *= linv;
    *reinterpret_cast<float4*>(dst + e * 4) = acc[e];
  }
}

extern "C" void kernel_launch(void* const* d_in, const int* in_sizes, int n_in,
                              void* d_out, int out_size, void* d_ws, size_t ws_size,
                              hipStream_t stream) {
  const float* X  = (const float*)d_in[0];
  const float* Wq = (const float*)d_in[1];
  const float* Wk = (const float*)d_in[2];
  const float* Wv = (const float*)d_in[3];
  float* out = (float*)d_out;

  unsigned short* qf = (unsigned short*)d_ws;          // frag-major Q [BT/16][4][64][8]
  unsigned short* kf = qf + (size_t)BT * DD;            // frag-major K [BT/32][2][4][64][8]
  unsigned short* vt = kf + (size_t)BT * DD;            // k-blocked V^T [BT/32][128][32]
  unsigned short* fq = vt + (size_t)BT * DD;            // frag-major W (16384 each)
  unsigned short* fk = fq + DD * DD;
  unsigned short* fv = fk + DD * DD;
  float* pO = (float*)(fv + DD * DD);                   // partials [4*128*4][32][128]
  float* pL = pO + (size_t)BATCH * 128 * MAXPARTS * 32 * 128;  // rowsums [...][32]

  dim3 wt_grid(64, 3);
  wt_kernel<<<wt_grid, 256, 0, stream>>>(Wq, Wk, Wv, fq, fk, fv);
  proj_kernel<<<BT / 32, 256, 0, stream>>>(X, fq, fk, fv, qf, kf, vt);
  attn_kernel<<<320, 256, 0, stream>>>(qf, kf, vt, pO, pL, out);
  comb_kernel<<<512, 256, 0, stream>>>(pO, pL, out);
}

// Round 9
// 113.762 us; speedup vs baseline: 1.0221x; 1.0221x over previous
//
#include <hip/hip_runtime.h>

#define T_SEQ 4096
#define BATCH 4
#define DD 128
#define BT (BATCH * T_SEQ)
#define MAXPARTS 4        // groups split into sg/8+1 <= 4 balanced parts

typedef __bf16 bf16x8 __attribute__((ext_vector_type(8)));
typedef float f32x4 __attribute__((ext_vector_type(4)));

__device__ inline bf16x8 ld8(const unsigned short* p) {
  return *reinterpret_cast<const bf16x8*>(p);
}
__device__ inline unsigned short bfc(float f) {
  __bf16 v = (__bf16)f;
  return __builtin_bit_cast(unsigned short, v);
}
__device__ inline float fexp2(float x) {
  float r;
  asm("v_exp_f32 %0, %1" : "=v"(r) : "v"(x));
  return r;
}
// V-buffer swizzle: XOR the 16B slot with (row>>1)&3 so 16 lanes reading
// different rows at one column hit distinct bank quads (residual 2-way
// aliasing is free). Row = 32 shorts = 64 B. Bits touched: 3-4 from 6-7,
// so the 4096-block-select bit (12) is unaffected.
__device__ inline int vsw(int sIdx) {
  return sIdx ^ ((((sIdx >> 6) & 3) << 3));
}

#define MFMA(a, b, c) __builtin_amdgcn_mfma_f32_16x16x32_bf16((a), (b), (c), 0, 0, 0)

// ---- W (128x128 f32, [d][u]) -> frag-major bf16:
// F[((n0*4+c)*64 + lane)*8 + j] = W[(c*32+g*8+j)*128 + n0*16+t], lane=(g<<4)|t.
__global__ void wt_kernel(const float* __restrict__ Wq, const float* __restrict__ Wk,
                          const float* __restrict__ Wv,
                          unsigned short* __restrict__ fq, unsigned short* __restrict__ fk,
                          unsigned short* __restrict__ fv) {
  const float* W = (blockIdx.y == 0) ? Wq : (blockIdx.y == 1) ? Wk : Wv;
  unsigned short* F = (blockIdx.y == 0) ? fq : (blockIdx.y == 1) ? fk : fv;
  int e = blockIdx.x * 256 + threadIdx.x;          // 0..16383
  int j = e & 7, lane = (e >> 3) & 63, nc = e >> 9;
  int c = nc & 3, n0 = nc >> 2;
  int t = lane & 15, g = lane >> 4;
  F[e] = bfc(W[(c * 32 + g * 8 + j) * 128 + n0 * 16 + t]);
}

// ---- projections, W-STATIONARY (unchanged, proven). qf folds (1/64)*log2(e).
__global__ __launch_bounds__(256) void proj_kernel(
    const float* __restrict__ X,
    const unsigned short* __restrict__ fq,
    const unsigned short* __restrict__ fk,
    const unsigned short* __restrict__ fv,
    unsigned short* __restrict__ qf,
    unsigned short* __restrict__ kf,
    unsigned short* __restrict__ vt) {
  const int tid = threadIdx.x;
  const int w = tid >> 6, lane = tid & 63;
  const int t = lane & 15, g = lane >> 4;
  const int r0 = blockIdx.x * 32;   // 512 blocks x 32 rows

  __shared__ unsigned short xs[2][16 * 136];

  bf16x8 wq[2][4], wk[2][4], wv[2][4];
#pragma unroll
  for (int s = 0; s < 2; ++s)
#pragma unroll
    for (int c = 0; c < 4; ++c) {
      int fo = (((w + s * 4) * 4 + c) * 64 + lane) * 8;
      wq[s][c] = ld8(fq + fo);
      wk[s][c] = ld8(fk + fo);
      wv[s][c] = ld8(fv + fo);
    }

#pragma unroll
  for (int sub = 0; sub < 2; ++sub) {
    int r = tid >> 4, cb = tid & 15;
    const float* xp = X + (size_t)(r0 + sub * 16 + r) * DD + cb * 8;
    float4 lo = *reinterpret_cast<const float4*>(xp);
    float4 hi = *reinterpret_cast<const float4*>(xp + 4);
    bf16x8 tmp;
    tmp[0] = (__bf16)lo.x; tmp[1] = (__bf16)lo.y; tmp[2] = (__bf16)lo.z; tmp[3] = (__bf16)lo.w;
    tmp[4] = (__bf16)hi.x; tmp[5] = (__bf16)hi.y; tmp[6] = (__bf16)hi.z; tmp[7] = (__bf16)hi.w;
    *reinterpret_cast<bf16x8*>(&xs[sub][r * 136 + cb * 8]) = tmp;
  }
  __syncthreads();

#pragma unroll
  for (int sub = 0; sub < 2; ++sub) {
    const int r0s = r0 + sub * 16;
    bf16x8 x[4];
#pragma unroll
    for (int c = 0; c < 4; ++c)
      x[c] = ld8(&xs[sub][t * 136 + c * 32 + g * 8]);

#pragma unroll
    for (int s = 0; s < 2; ++s) {
      const int n0 = w + s * 4;
      f32x4 aq = {0.f, 0.f, 0.f, 0.f}, ak = {0.f, 0.f, 0.f, 0.f};
#pragma unroll
      for (int c = 0; c < 4; ++c) {
        aq = MFMA(x[c], wq[s][c], aq);
        ak = MFMA(x[c], wk[s][c], ak);
      }
      const int cP = n0 >> 1;
      const int Gp = ((n0 & 1) << 1) | (t >> 3);
      const int ep = t & 7;
#pragma unroll
      for (int r = 0; r < 4; ++r) {
        int row = r0s + g * 4 + r;
        size_t qoff = ((size_t)((row >> 4) * 4 + cP) * 64 + ((Gp << 4) | (row & 15))) * 8 + ep;
        qf[qoff] = bfc(aq[r] * 0.0225421101f);   // (1/64) * log2(e)
        int tp = (row & 3) | (((row >> 3) & 3) << 2);
        size_t koff =
            ((size_t)(((row >> 5) * 2 + ((row >> 2) & 1)) * 4 + cP) * 64 + ((Gp << 4) | tp)) * 8 +
            ep;
        kf[koff] = bfc(ak[r]);
      }
    }

    const int key = r0s + t;
    const size_t vbase = (size_t)(key >> 5) * 4096 + (key & 31);
#pragma unroll
    for (int s = 0; s < 2; ++s) {
      const int u0 = w + s * 4;
      f32x4 av = {0.f, 0.f, 0.f, 0.f};
#pragma unroll
      for (int c = 0; c < 4; ++c)
        av = MFMA(wv[s][c], x[c], av);
#pragma unroll
      for (int r = 0; r < 4; ++r)
        vt[vbase + (size_t)(u0 * 16 + g * 4 + r) * 32] = bfc(av[r]);
    }
  }
}

// ---- flash attention, LDS-shared K/V, KVBLK=64: a block's 4 waves process
// the SAME 64-key chunk (two 32-key sub-chunks) for the 4 tiles of one
// 128-row q-group (wave w owns tile 4*sg+w). Per iteration the block stages
// 32 KB once (reg-staged split, double-buffered) with ONE barrier per 64
// keys -- r8 paid a barrier per 32 keys; per-iteration overhead (barrier
// drain, staging issue, loop VALU) halves per byte, and the ~2x compute
// window hides the staged loads' L2 latency. s_setprio(1) wraps the MFMA
// clusters (T5, +4-7% measured on attn). Decomposition identical to r8:
// group sg splits into sg/8+1 <= 4 balanced parts, 80 blocks/batch, grid
// 320; worst block 16 iterations (was 32). Split groups write raw per-wave
// partials (18 MB total); comb_kernel finishes them.
__global__ __launch_bounds__(256, 2) void attn_kernel(
    const unsigned short* __restrict__ qf,
    const unsigned short* __restrict__ kf,
    const unsigned short* __restrict__ vt,
    float* __restrict__ pO,
    float* __restrict__ pL,
    float* __restrict__ out) {
  const int tid = threadIdx.x;
  const int w = tid >> 6, lane = tid & 63;
  const int t = lane & 15, G = lane >> 4;
  const int bi = blockIdx.x;
  const int xcd = bi & 7;                      // assumed round-robin XCD mapping
  const int b = xcd >> 1;                      // batch pinned to an XCD pair (L2)
  const int k = ((bi >> 3) << 1) | (xcd & 1);  // 0..79 batch-local block index

  // decode: a=79-k ascending-enum index -> (octet o, group sg, part p)
  const int a = 79 - k;
  int o = 0;
  while (4 * (o + 1) * (o + 2) <= a) ++o;      // o in 0..3
  const int idx = a - 4 * o * (o + 1);
  const int sg = 8 * o + idx / (o + 1);
  const int p = idx % (o + 1);
  const int parts = o + 1;
  const int N = 2 * sg + 2;                    // 64-key chunks in this group
  const int qn = N / parts, rem = N % parts;   // balanced split
  const int jlo = p * qn + min(p, rem);
  const int jhi = jlo + qn + (p < rem ? 1 : 0);

  const int sig32 = 4 * sg + w;                // this wave's 32-row tile
  const int q0 = sig32 * 32;

  const unsigned short* kfb = kf + (size_t)b * (T_SEQ * DD);
  const unsigned short* vtb = vt + (size_t)b * (T_SEQ * DD);

  __shared__ unsigned short bufK[2][8192], bufV[2][8192];

  // Q fragments for tiles 2*sig32, 2*sig32+1
  bf16x8 qa[2][4];
#pragma unroll
  for (int pp = 0; pp < 2; ++pp)
#pragma unroll
    for (int c = 0; c < 4; ++c)
      qa[pp][c] = ld8(qf + ((size_t)((b * 256 + 2 * sig32 + pp) * 4 + c) * 64 + lane) * 8);

  f32x4 O[2][8];
#pragma unroll
  for (int pp = 0; pp < 2; ++pp)
#pragma unroll
    for (int u0 = 0; u0 < 8; ++u0) O[pp][u0] = (f32x4){0.f, 0.f, 0.f, 0.f};
  float ls0 = 0.f, ls1 = 0.f;

  // ---- prologue: stage chunk jlo into buf 0 (32KB: each thread 8 x 16B)
  bf16x8 st[8];
  {
    const unsigned short* kch = kfb + (size_t)jlo * 8192;
    const unsigned short* vch = vtb + (size_t)jlo * 8192;
#pragma unroll
    for (int i = 0; i < 4; ++i) {
      st[i]     = ld8(kch + i * 2048 + tid * 8);
      st[4 + i] = ld8(vch + i * 2048 + tid * 8);
    }
#pragma unroll
    for (int i = 0; i < 4; ++i) {
      *reinterpret_cast<bf16x8*>(&bufK[0][i * 2048 + tid * 8]) = st[i];
      *reinterpret_cast<bf16x8*>(&bufV[0][vsw(i * 2048 + tid * 8)]) = st[4 + i];
    }
  }
  __syncthreads();

  int cur = 0;
  for (int j = jlo; j < jhi; ++j) {
    const bool more = (j + 1 < jhi);
    // issue next-chunk stage loads (consumed by ds_write after compute)
    if (more) {
      const unsigned short* kch = kfb + (size_t)(j + 1) * 8192;
      const unsigned short* vch = vtb + (size_t)(j + 1) * 8192;
#pragma unroll
      for (int i = 0; i < 4; ++i) {
        st[i]     = ld8(kch + i * 2048 + tid * 8);
        st[4 + i] = ld8(vch + i * 2048 + tid * 8);
      }
    }

    // ---- two 32-key sub-chunks from LDS
#pragma unroll
    for (int sub = 0; sub < 2; ++sub) {
      const int c32 = 2 * j + sub;
      if (c32 <= sig32) {                      // wave-uniform
        const int base = sub * 4096;
        f32x4 s00 = {0.f, 0.f, 0.f, 0.f}, s01 = {0.f, 0.f, 0.f, 0.f};
        f32x4 s10 = {0.f, 0.f, 0.f, 0.f}, s11 = {0.f, 0.f, 0.f, 0.f};
        {
          bf16x8 kc[4];
#pragma unroll
          for (int c = 0; c < 4; ++c) kc[c] = ld8(&bufK[cur][base + c * 512 + lane * 8]);
          __builtin_amdgcn_s_setprio(1);
#pragma unroll
          for (int c = 0; c < 4; ++c) {
            s00 = MFMA(kc[c], qa[0][c], s00);
            s10 = MFMA(kc[c], qa[1][c], s10);
          }
          __builtin_amdgcn_s_setprio(0);
#pragma unroll
          for (int c = 0; c < 4; ++c) kc[c] = ld8(&bufK[cur][base + (4 + c) * 512 + lane * 8]);
          __builtin_amdgcn_s_setprio(1);
#pragma unroll
          for (int c = 0; c < 4; ++c) {
            s01 = MFMA(kc[c], qa[0][c], s01);
            s11 = MFMA(kc[c], qa[1][c], s11);
          }
          __builtin_amdgcn_s_setprio(0);
        }

        bf16x8 pb0, pb1;
        if (c32 < sig32) {
          // fully-unmasked sub-chunk: no causal compares
#pragma unroll
          for (int r = 0; r < 4; ++r) {
            float e00 = fexp2(s00[r]), e01 = fexp2(s01[r]);
            float e10 = fexp2(s10[r]), e11 = fexp2(s11[r]);
            ls0 += e00 + e01;
            ls1 += e10 + e11;
            pb0[r] = (__bf16)e00; pb0[r + 4] = (__bf16)e01;
            pb1[r] = (__bf16)e10; pb1[r + 4] = (__bf16)e11;
          }
        } else {
          // diagonal sub-chunk (c32 == sig32)
#pragma unroll
          for (int r = 0; r < 4; ++r) {
            int k0 = c32 * 32 + G * 8 + r;
            float e00 = (k0 <= q0 + t) ? fexp2(s00[r]) : 0.f;
            float e01 = (k0 + 4 <= q0 + t) ? fexp2(s01[r]) : 0.f;
            float e10 = (k0 <= q0 + 16 + t) ? fexp2(s10[r]) : 0.f;
            float e11 = (k0 + 4 <= q0 + 16 + t) ? fexp2(s11[r]) : 0.f;
            ls0 += e00 + e01;
            ls1 += e10 + e11;
            pb0[r] = (__bf16)e00; pb0[r + 4] = (__bf16)e01;
            pb1[r] = (__bf16)e10; pb1[r + 4] = (__bf16)e11;
          }
        }

        __builtin_amdgcn_s_setprio(1);
#pragma unroll
        for (int u0 = 0; u0 < 8; ++u0) {
          bf16x8 vcu = ld8(&bufV[cur][base + vsw((u0 * 16 + t) * 32 + G * 8)]);
          O[0][u0] = MFMA(pb0, vcu, O[0][u0]);
          O[1][u0] = MFMA(pb1, vcu, O[1][u0]);
        }
        __builtin_amdgcn_s_setprio(0);
      }
    }

    // ---- write staged chunk j+1 into the other buffer, then barrier
    if (more) {
      const int nxt = cur ^ 1;
#pragma unroll
      for (int i = 0; i < 4; ++i) {
        *reinterpret_cast<bf16x8*>(&bufK[nxt][i * 2048 + tid * 8]) = st[i];
        *reinterpret_cast<bf16x8*>(&bufV[nxt][vsw(i * 2048 + tid * 8)]) = st[4 + i];
      }
      __syncthreads();
      cur ^= 1;
    }
  }

  // ---- epilogue: one flush per block
  float r0s = ls0; r0s += __shfl_xor(r0s, 16); r0s += __shfl_xor(r0s, 32);
  float r1s = ls1; r1s += __shfl_xor(r1s, 16); r1s += __shfl_xor(r1s, 32);
  if (parts == 1) {
    // whole group in this block: each wave normalizes + stores its tile
    float linv0[4], linv1[4];
#pragma unroll
    for (int r = 0; r < 4; ++r) {
      linv0[r] = 1.0f / __shfl(r0s, G * 4 + r);
      linv1[r] = 1.0f / __shfl(r1s, G * 4 + r);
    }
    float* op0 = out + ((size_t)(b * T_SEQ + q0 + G * 4)) * DD + t;
    float* op1 = op0 + (size_t)16 * DD;
#pragma unroll
    for (int u0 = 0; u0 < 8; ++u0) {
#pragma unroll
      for (int r = 0; r < 4; ++r) {
        op0[(size_t)r * DD + u0 * 16] = O[0][u0][r] * linv0[r];
        op1[(size_t)r * DD + u0 * 16] = O[1][u0][r] * linv1[r];
      }
    }
  } else {
    // split group: raw per-wave partial to workspace slot (b, sig32, p)
    const int slot = (b * 128 + sig32) * MAXPARTS + p;
    if (lane < 16) {
      pL[slot * 32 + lane] = r0s;
      pL[slot * 32 + 16 + lane] = r1s;
    }
    float* pb = pO + (size_t)slot * 4096 + (size_t)(G * 4) * DD + t;
#pragma unroll
    for (int u0 = 0; u0 < 8; ++u0) {
#pragma unroll
      for (int r = 0; r < 4; ++r) {
        pb[(size_t)r * DD + u0 * 16] = O[0][u0][r];
        pb[(size_t)(16 + r) * DD + u0 * 16] = O[1][u0][r];
      }
    }
  }
}

// ---- combine split groups: sum <=4 per-part partials, normalize, store.
__global__ __launch_bounds__(256) void comb_kernel(const float* __restrict__ pO,
                                                   const float* __restrict__ pL,
                                                   float* __restrict__ out) {
  const int bi = blockIdx.x;          // 512: b = bi>>7, sig32 = bi&127
  const int b = bi >> 7, sig32 = bi & 127;
  const int sg = sig32 >> 2;
  const int parts = sg / 8 + 1;
  if (parts == 1) return;             // handled directly by attn_kernel
  const int tid = threadIdx.x;
  const int q = tid >> 3, uc = (tid & 7) * 16;
  const int slot0 = (b * 128 + sig32) * MAXPARTS;

  float ls = 0.f;
  for (int p = 0; p < parts; ++p) ls += pL[(slot0 + p) * 32 + q];
  const float linv = 1.0f / ls;

  float4 acc[4] = {{0,0,0,0},{0,0,0,0},{0,0,0,0},{0,0,0,0}};
  for (int p = 0; p < parts; ++p) {
    const float* src = pO + (size_t)(slot0 + p) * 4096 + (size_t)q * DD + uc;
#pragma unroll
    for (int e = 0; e < 4; ++e) {
      float4 v = *reinterpret_cast<const float4*>(src + e * 4);
      acc[e].x += v.x; acc[e].y += v.y; acc[e].z += v.z; acc[e].w += v.w;
    }
  }
  float* dst = out + ((size_t)(b * T_SEQ + sig32 * 32 + q)) * DD + uc;
#pragma unroll
  for (int e = 0; e < 4; ++e) {
    acc[e].x *= linv; acc[e].y *= linv; acc[e].z *= linv; acc[e].w *= linv;
    *reinterpret_cast<float4*>(dst + e * 4) = acc[e];
  }
}

extern "C" void kernel_launch(void* const* d_in, const int* in_sizes, int n_in,
                              void* d_out, int out_size, void* d_ws, size_t ws_size,
                              hipStream_t stream) {
  const float* X  = (const float*)d_in[0];
  const float* Wq = (const float*)d_in[1];
  const float* Wk = (const float*)d_in[2];
  const float* Wv = (const float*)d_in[3];
  float* out = (float*)d_out;

  unsigned short* qf = (unsigned short*)d_ws;          // frag-major Q [BT/16][4][64][8]
  unsigned short* kf = qf + (size_t)BT * DD;            // frag-major K [BT/32][2][4][64][8]
  unsigned short* vt = kf + (size_t)BT * DD;            // k-blocked V^T [BT/32][128][32]
  unsigned short* fq = vt + (size_t)BT * DD;            // frag-major W (16384 each)
  unsigned short* fk = fq + DD * DD;
  unsigned short* fv = fk + DD * DD;
  float* pO = (float*)(fv + DD * DD);                   // partials [4*128*4][32][128]
  float* pL = pO + (size_t)BATCH * 128 * MAXPARTS * 32 * 128;  // rowsums [...][32]

  dim3 wt_grid(64, 3);
  wt_kernel<<<wt_grid, 256, 0, stream>>>(Wq, Wk, Wv, fq, fk, fv);
  proj_kernel<<<BT / 32, 256, 0, stream>>>(X, fq, fk, fv, qf, kf, vt);
  attn_kernel<<<320, 256, 0, stream>>>(qf, kf, vt, pO, pL, out);
  comb_kernel<<<512, 256, 0, stream>>>(pO, pL, out);
}